// Round 3
// baseline (712.784 us; speedup 1.0000x reference)
//
#include <hip/hip_runtime.h>

// GPS layer: GCNConv (self-loops, symmetric norm) + positional-encoding linear.
// N=100000 nodes, E=1600000 edges, IN=128, OUT=64, POS=64. All f32.

#define THREADS 256

// deg[i] = 1 (self loop) -- init
__global__ void deg_init_kernel(float* __restrict__ deg, int N) {
    int i = blockIdx.x * blockDim.x + threadIdx.x;
    if (i < N) deg[i] = 1.0f;
}

// deg[dst[e]] += 1 for every edge
__global__ void deg_acc_kernel(const int* __restrict__ dst, float* __restrict__ deg, int E) {
    int e = blockIdx.x * blockDim.x + threadIdx.x;
    if (e < E) atomicAdd(&deg[dst[e]], 1.0f);
}

// in-place deg -> rsqrt(deg)   (deg >= 1 always, so no zero guard needed)
__global__ void dinv_kernel(float* __restrict__ deg, int N) {
    int i = blockIdx.x * blockDim.x + threadIdx.x;
    if (i < N) deg[i] = rsqrtf(deg[i]);
}

// h = x @ W   ([N,128] x [128,64]); one thread per output element, W staged in LDS.
__global__ void gemm_xw_kernel(const float* __restrict__ x, const float* __restrict__ W,
                               float* __restrict__ h, int N) {
    __shared__ float Ws[128 * 64];
    for (int i = threadIdx.x; i < 128 * 64; i += blockDim.x) Ws[i] = W[i];
    __syncthreads();
    int idx = blockIdx.x * blockDim.x + threadIdx.x;
    int total = N * 64;
    if (idx >= total) return;
    int row = idx >> 6, col = idx & 63;
    const float4* xr = (const float4*)(x + (size_t)row * 128);
    float acc = 0.0f;
#pragma unroll
    for (int k4 = 0; k4 < 32; ++k4) {
        float4 xv = xr[k4];
        acc = fmaf(xv.x, Ws[(k4 * 4 + 0) * 64 + col], acc);
        acc = fmaf(xv.y, Ws[(k4 * 4 + 1) * 64 + col], acc);
        acc = fmaf(xv.z, Ws[(k4 * 4 + 2) * 64 + col], acc);
        acc = fmaf(xv.w, Ws[(k4 * 4 + 3) * 64 + col], acc);
    }
    h[idx] = acc;
}

// out = pos @ Wp + bp + b + dinv^2 * h   (self-loop term fused here so the
// scatter kernel only handles real edges)
__global__ void out_init_kernel(const float* __restrict__ pos, const float* __restrict__ Wp,
                                const float* __restrict__ bp, const float* __restrict__ b,
                                const float* __restrict__ h, const float* __restrict__ dinv,
                                float* __restrict__ out, int N) {
    __shared__ float Ws[64 * 64];
    for (int i = threadIdx.x; i < 64 * 64; i += blockDim.x) Ws[i] = Wp[i];
    __syncthreads();
    int idx = blockIdx.x * blockDim.x + threadIdx.x;
    int total = N * 64;
    if (idx >= total) return;
    int row = idx >> 6, col = idx & 63;
    const float4* pr = (const float4*)(pos + (size_t)row * 64);
    float acc = b[col] + bp[col];
#pragma unroll
    for (int k4 = 0; k4 < 16; ++k4) {
        float4 pv = pr[k4];
        acc = fmaf(pv.x, Ws[(k4 * 4 + 0) * 64 + col], acc);
        acc = fmaf(pv.y, Ws[(k4 * 4 + 1) * 64 + col], acc);
        acc = fmaf(pv.z, Ws[(k4 * 4 + 2) * 64 + col], acc);
        acc = fmaf(pv.w, Ws[(k4 * 4 + 3) * 64 + col], acc);
    }
    float di = dinv[row];
    out[idx] = acc + di * di * h[idx];
}

// out[dst] += h[src] * dinv[src]*dinv[dst]; 64 threads (one per channel) per edge.
__global__ void scatter_kernel(const int* __restrict__ src, const int* __restrict__ dst,
                               const float* __restrict__ h, const float* __restrict__ dinv,
                               float* __restrict__ out, int E) {
    int t = blockIdx.x * blockDim.x + threadIdx.x;
    int e = t >> 6;
    int c = t & 63;
    if (e < E) {
        int s = src[e];
        int d = dst[e];
        float nrm = dinv[s] * dinv[d];
        atomicAdd(&out[(size_t)d * 64 + c], h[(size_t)s * 64 + c] * nrm);
    }
}

extern "C" void kernel_launch(void* const* d_in, const int* in_sizes, int n_in,
                              void* d_out, int out_size, void* d_ws, size_t ws_size,
                              hipStream_t stream) {
    const float* x   = (const float*)d_in[0];   // [N,128]
    const int*   ei  = (const int*)d_in[1];     // [2,E]
    const float* pos = (const float*)d_in[2];   // [N,64]
    const float* W   = (const float*)d_in[3];   // [128,64]
    const float* b   = (const float*)d_in[4];   // [64]
    const float* Wp  = (const float*)d_in[5];   // [64,64]
    const float* bp  = (const float*)d_in[6];   // [64]
    float* out = (float*)d_out;

    const int N = in_sizes[0] / 128;            // 100000
    const int E = in_sizes[1] / 2;              // 1600000
    const int* srcp = ei;
    const int* dstp = ei + E;

    // workspace: h [N*64] then deg/dinv [N]
    float* h   = (float*)d_ws;
    float* deg = h + (size_t)N * 64;

    deg_init_kernel<<<(N + THREADS - 1) / THREADS, THREADS, 0, stream>>>(deg, N);
    deg_acc_kernel<<<(E + THREADS - 1) / THREADS, THREADS, 0, stream>>>(dstp, deg, E);
    dinv_kernel<<<(N + THREADS - 1) / THREADS, THREADS, 0, stream>>>(deg, N);

    int totalNO = N * 64;
    gemm_xw_kernel<<<(totalNO + THREADS - 1) / THREADS, THREADS, 0, stream>>>(x, W, h, N);
    out_init_kernel<<<(totalNO + THREADS - 1) / THREADS, THREADS, 0, stream>>>(
        pos, Wp, bp, b, h, deg, out, N);

    long long totalEC = (long long)E * 64;
    int blocks = (int)((totalEC + THREADS - 1) / THREADS);
    scatter_kernel<<<blocks, THREADS, 0, stream>>>(srcp, dstp, h, deg, out, E);
}

// Round 4
// 417.209 us; speedup vs baseline: 1.7085x; 1.7085x over previous
//
#include <hip/hip_runtime.h>

// GPS layer: GCNConv (self-loops, symmetric norm) + positional-encoding linear.
// N=100000 nodes, E=1600000 edges, IN=128, OUT=64, POS=64. All f32.
// Round 3: CSR-based gather instead of 102M f32 atomics.

#define THREADS 256
#define SCAN_BLK 256
#define SCAN_ELEMS 4           // 1024 elements per scan block
#define SCAN_TILE (SCAN_BLK * SCAN_ELEMS)

// cnt[i] = 0
__global__ void cnt_init_kernel(int* __restrict__ cnt, int N) {
    int i = blockIdx.x * blockDim.x + threadIdx.x;
    if (i < N) cnt[i] = 0;
}

// cnt[dst[e]]++ (in-degree, excluding self loop)
__global__ void cnt_acc_kernel(const int* __restrict__ dst, int* __restrict__ cnt, int E) {
    int e = blockIdx.x * blockDim.x + threadIdx.x;
    if (e < E) atomicAdd(&cnt[dst[e]], 1);
}

// per-block exclusive scan of cnt -> offs, block totals -> blocksums.
// Also computes dinv[i] = rsqrt(cnt[i]+1) and zeroes cursor[i].
__global__ void scan1_kernel(const int* __restrict__ cnt, int* __restrict__ offs,
                             int* __restrict__ blocksums, float* __restrict__ dinv,
                             int* __restrict__ cursor, int N) {
    __shared__ int lds[SCAN_BLK];
    int t = threadIdx.x;
    int base = blockIdx.x * SCAN_TILE + t * SCAN_ELEMS;
    int v[SCAN_ELEMS];
    int sum = 0;
#pragma unroll
    for (int i = 0; i < SCAN_ELEMS; ++i) {
        int idx = base + i;
        int c = (idx < N) ? cnt[idx] : 0;
        v[i] = sum;
        sum += c;
        if (idx < N) {
            dinv[idx] = rsqrtf((float)(c + 1));
            cursor[idx] = 0;
        }
    }
    lds[t] = sum;
    __syncthreads();
    for (int off = 1; off < SCAN_BLK; off <<= 1) {
        int add = (t >= off) ? lds[t - off] : 0;
        __syncthreads();
        lds[t] += add;
        __syncthreads();
    }
    int texcl = (t > 0) ? lds[t - 1] : 0;
#pragma unroll
    for (int i = 0; i < SCAN_ELEMS; ++i) {
        int idx = base + i;
        if (idx < N) offs[idx] = texcl + v[i];
    }
    if (t == SCAN_BLK - 1) blocksums[blockIdx.x] = lds[t];
}

// single-block exclusive scan of the (<=1024) block sums
__global__ void scan2_kernel(int* __restrict__ blocksums, int nb) {
    __shared__ int lds[1024];
    int t = threadIdx.x;
    lds[t] = (t < nb) ? blocksums[t] : 0;
    __syncthreads();
    for (int off = 1; off < 1024; off <<= 1) {
        int add = (t >= off) ? lds[t - off] : 0;
        __syncthreads();
        lds[t] += add;
        __syncthreads();
    }
    if (t < nb) blocksums[t] = (t > 0) ? lds[t - 1] : 0;
}

// offs[i] += scanned block base
__global__ void scan3_kernel(int* __restrict__ offs, const int* __restrict__ blocksums, int N) {
    int i = blockIdx.x * blockDim.x + threadIdx.x;
    if (i < N) offs[i] += blocksums[i / SCAN_TILE];
}

// csr_src[offs[dst[e]] + cursor[dst[e]]++] = src[e]
__global__ void fill_kernel(const int* __restrict__ src, const int* __restrict__ dst,
                            const int* __restrict__ offs, int* __restrict__ cursor,
                            int* __restrict__ csr_src, int E) {
    int e = blockIdx.x * blockDim.x + threadIdx.x;
    if (e < E) {
        int d = dst[e];
        int p = offs[d] + atomicAdd(&cursor[d], 1);
        csr_src[p] = src[e];
    }
}

// h = x @ W   ([N,128] x [128,64]); 4 cols per thread, W staged in LDS (b128 reads).
__global__ void gemm_xw_kernel(const float* __restrict__ x, const float* __restrict__ W,
                               float* __restrict__ h, int N) {
    __shared__ float Ws[128 * 64];
    for (int i = threadIdx.x; i < 128 * 64; i += blockDim.x) Ws[i] = W[i];
    __syncthreads();
    int idx = blockIdx.x * blockDim.x + threadIdx.x;
    int total = N * 16;
    if (idx >= total) return;
    int row = idx >> 4, c4 = (idx & 15) * 4;
    const float4* xr = (const float4*)(x + (size_t)row * 128);
    float4 acc = {0.f, 0.f, 0.f, 0.f};
#pragma unroll
    for (int k4 = 0; k4 < 32; ++k4) {
        float4 xv = xr[k4];
        float xs[4] = {xv.x, xv.y, xv.z, xv.w};
#pragma unroll
        for (int kk = 0; kk < 4; ++kk) {
            float4 wv = *(const float4*)&Ws[(k4 * 4 + kk) * 64 + c4];
            acc.x = fmaf(xs[kk], wv.x, acc.x);
            acc.y = fmaf(xs[kk], wv.y, acc.y);
            acc.z = fmaf(xs[kk], wv.z, acc.z);
            acc.w = fmaf(xs[kk], wv.w, acc.w);
        }
    }
    *(float4*)&h[(size_t)row * 64 + c4] = acc;
}

// out = pos @ Wp + bp + b + dinv^2 * h   (self-loop term fused)
__global__ void out_init_kernel(const float* __restrict__ pos, const float* __restrict__ Wp,
                                const float* __restrict__ bp, const float* __restrict__ b,
                                const float* __restrict__ h, const float* __restrict__ dinv,
                                float* __restrict__ out, int N) {
    __shared__ float Ws[64 * 64];
    for (int i = threadIdx.x; i < 64 * 64; i += blockDim.x) Ws[i] = Wp[i];
    __syncthreads();
    int idx = blockIdx.x * blockDim.x + threadIdx.x;
    int total = N * 16;
    if (idx >= total) return;
    int row = idx >> 4, c4 = (idx & 15) * 4;
    const float4* pr = (const float4*)(pos + (size_t)row * 64);
    float4 acc;
    acc.x = b[c4 + 0] + bp[c4 + 0];
    acc.y = b[c4 + 1] + bp[c4 + 1];
    acc.z = b[c4 + 2] + bp[c4 + 2];
    acc.w = b[c4 + 3] + bp[c4 + 3];
#pragma unroll
    for (int k4 = 0; k4 < 16; ++k4) {
        float4 pv = pr[k4];
        float ps[4] = {pv.x, pv.y, pv.z, pv.w};
#pragma unroll
        for (int kk = 0; kk < 4; ++kk) {
            float4 wv = *(const float4*)&Ws[(k4 * 4 + kk) * 64 + c4];
            acc.x = fmaf(ps[kk], wv.x, acc.x);
            acc.y = fmaf(ps[kk], wv.y, acc.y);
            acc.z = fmaf(ps[kk], wv.z, acc.z);
            acc.w = fmaf(ps[kk], wv.w, acc.w);
        }
    }
    float di = dinv[row];
    float dd = di * di;
    float4 hv = *(const float4*)&h[(size_t)row * 64 + c4];
    acc.x += dd * hv.x;
    acc.y += dd * hv.y;
    acc.z += dd * hv.z;
    acc.w += dd * hv.w;
    *(float4*)&out[(size_t)row * 64 + c4] = acc;
}

// one wave per node: out[d][c] += dinv[d] * sum_j dinv[s_j] * h[s_j][c]
__global__ void gather_kernel(const int* __restrict__ csr_src, const int* __restrict__ offs,
                              const int* __restrict__ cnt, const float* __restrict__ h,
                              const float* __restrict__ dinv, float* __restrict__ out, int N) {
    int wid = (int)((blockIdx.x * (size_t)blockDim.x + threadIdx.x) >> 6);
    int c = threadIdx.x & 63;
    if (wid >= N) return;
    int beg = offs[wid];
    int num = cnt[wid];
    float acc = 0.0f;
    for (int j = 0; j < num; ++j) {
        int s = csr_src[beg + j];           // wave-uniform broadcast load
        acc = fmaf(dinv[s], h[(size_t)s * 64 + c], acc);
    }
    size_t o = (size_t)wid * 64 + c;
    out[o] = fmaf(dinv[wid], acc, out[o]);  // non-atomic: this wave owns row wid
}

extern "C" void kernel_launch(void* const* d_in, const int* in_sizes, int n_in,
                              void* d_out, int out_size, void* d_ws, size_t ws_size,
                              hipStream_t stream) {
    const float* x   = (const float*)d_in[0];   // [N,128]
    const int*   ei  = (const int*)d_in[1];     // [2,E]
    const float* pos = (const float*)d_in[2];   // [N,64]
    const float* W   = (const float*)d_in[3];   // [128,64]
    const float* b   = (const float*)d_in[4];   // [64]
    const float* Wp  = (const float*)d_in[5];   // [64,64]
    const float* bp  = (const float*)d_in[6];   // [64]
    float* out = (float*)d_out;

    const int N = in_sizes[0] / 128;            // 100000
    const int E = in_sizes[1] / 2;              // 1600000
    const int* srcp = ei;
    const int* dstp = ei + E;

    // workspace layout (all f32/int32, 4B aligned):
    float* h         = (float*)d_ws;                 // N*64
    float* dinv      = h + (size_t)N * 64;           // N
    int*   cnt       = (int*)(dinv + N);             // N
    int*   offs      = cnt + N;                      // N
    int*   cursor    = offs + N;                     // N
    int*   blocksums = cursor + N;                   // 1024
    int*   csr_src   = blocksums + 1024;             // E

    int nbN  = (N + THREADS - 1) / THREADS;
    int nbE  = (E + THREADS - 1) / THREADS;
    int nbS  = (N + SCAN_TILE - 1) / SCAN_TILE;      // scan blocks (98), must be <= 1024

    cnt_init_kernel<<<nbN, THREADS, 0, stream>>>(cnt, N);
    cnt_acc_kernel<<<nbE, THREADS, 0, stream>>>(dstp, cnt, E);
    scan1_kernel<<<nbS, SCAN_BLK, 0, stream>>>(cnt, offs, blocksums, dinv, cursor, N);
    scan2_kernel<<<1, 1024, 0, stream>>>(blocksums, nbS);
    scan3_kernel<<<nbN, THREADS, 0, stream>>>(offs, blocksums, N);
    fill_kernel<<<nbE, THREADS, 0, stream>>>(srcp, dstp, offs, cursor, csr_src, E);

    int totalT = N * 16;                              // 4 cols per thread
    int nbG = (totalT + THREADS - 1) / THREADS;
    gemm_xw_kernel<<<nbG, THREADS, 0, stream>>>(x, W, h, N);
    out_init_kernel<<<nbG, THREADS, 0, stream>>>(pos, Wp, bp, b, h, dinv, out, N);

    long long totalGC = (long long)N * 64;
    int nbGa = (int)((totalGC + THREADS - 1) / THREADS);
    gather_kernel<<<nbGa, THREADS, 0, stream>>>(csr_src, offs, cnt, h, dinv, out, N);
}